// Round 15
// baseline (277.270 us; speedup 1.0000x reference)
//
#include <hip/hip_runtime.h>
#include <hip/hip_bf16.h>

typedef __attribute__((ext_vector_type(8))) short bf16x8;
typedef __attribute__((ext_vector_type(4))) short bf16x4;
typedef __attribute__((ext_vector_type(4))) float f32x4;

constexpr int cH = 16, cD = 128, cHID = 2048, cS = 2048, cB = 2;
constexpr float cEPS = 1.1920928955078125e-07f;
constexpr float cQS = 0.08838834764831845f * 1.442695040888963f; // 1/sqrt(D)*log2(e)

// manual RNE fp32->bf16 (3 VALU ops; __float2bfloat16 does NOT inline well — R6 regression)
__device__ __forceinline__ unsigned short f2bf(float f) {
  union { float f; unsigned u; } v; v.f = f;
  unsigned r = v.u + 0x7fffu + ((v.u >> 16) & 1u);
  return (unsigned short)(r >> 16);
}
__device__ __forceinline__ unsigned pk2(float a, float b) {
  return (unsigned)f2bf(a) | ((unsigned)f2bf(b) << 16);
}
__device__ __forceinline__ unsigned cvtpk(float a, float b) {
  unsigned r;
  asm("v_cvt_pk_bf16_f32 %0, %1, %2" : "=v"(r) : "v"(a), "v"(b));
  return r;
}
__device__ __forceinline__ f32x4 mfma16(bf16x8 a, bf16x8 b, f32x4 c) {
  return __builtin_amdgcn_mfma_f32_16x16x32_bf16(a, b, c, 0, 0, 0);
}
__device__ __forceinline__ f32x4 mfma16k16(bf16x4 a, bf16x4 b, f32x4 c) {
#if __has_builtin(__builtin_amdgcn_mfma_f32_16x16x16bf16_1k)
  return __builtin_amdgcn_mfma_f32_16x16x16bf16_1k(a, b, c, 0, 0, 0);
#else
  f32x4 d;
  asm volatile("v_mfma_f32_16x16x16_bf16 %0, %1, %2, %3\n\ts_nop 7\n\ts_nop 2"
               : "=v"(d) : "v"(a), "v"(b), "v"(c));
  return d;
#endif
}
// async global->LDS, 16B per lane; lds ptr must be wave-uniform base.
__device__ __forceinline__ void gl2l(const void* g, void* l) {
  __builtin_amdgcn_global_load_lds(
      (const __attribute__((address_space(1))) unsigned int*)g,
      (__attribute__((address_space(3))) unsigned int*)l, 16, 0, 0);
}

// -------- cvt fp32 -> bf16 (x, wq, wk, wv, wo concatenated) --------
__global__ __launch_bounds__(256) void cvt_all(
    const float* __restrict__ x, const float* __restrict__ wq,
    const float* __restrict__ wk, const float* __restrict__ wv,
    const float* __restrict__ wo,
    unsigned short* __restrict__ xb, unsigned short* __restrict__ wqb,
    unsigned short* __restrict__ wkb, unsigned short* __restrict__ wvb,
    unsigned short* __restrict__ wob)
{
  long i = (long)blockIdx.x * 2048 + threadIdx.x * 8;
  const float* s; unsigned short* d; long off;
  if (i < 8388608)       { s = x;  d = xb;  off = i; }
  else if (i < 12582912) { s = wq; d = wqb; off = i - 8388608; }
  else if (i < 12845056) { s = wk; d = wkb; off = i - 12582912; }
  else if (i < 13107200) { s = wv; d = wvb; off = i - 12845056; }
  else                   { s = wo; d = wob; off = i - 13107200; }
  float4 v0 = *reinterpret_cast<const float4*>(s + off);
  float4 v1 = *reinterpret_cast<const float4*>(s + off + 4);
  uint4 o; o.x = pk2(v0.x, v0.y); o.y = pk2(v0.z, v0.w);
  o.z = pk2(v1.x, v1.y); o.w = pk2(v1.z, v1.w);
  *reinterpret_cast<uint4*>(d + off) = o;
}

// -------- QKV GEMM (m97 structure) + register RoPE/RMSNorm epilogue --------
__global__ __launch_bounds__(256) void gemm_qkv(
    const unsigned short* __restrict__ A,    // xb [4096][2048]
    const unsigned short* __restrict__ Wq,   // [2048][2048]
    const unsigned short* __restrict__ Wk,   // [128][2048]
    const unsigned short* __restrict__ Wv,   // [128][2048]
    const float* __restrict__ cosb, const float* __restrict__ sinb,
    unsigned short* __restrict__ Qn,         // [B][H][S][D]
    unsigned short* __restrict__ Kn,         // [B][S][D] swizzled
    unsigned short* __restrict__ Vn)         // [B][S][D]
{
  __shared__ unsigned short lds[8192];       // A[128][32] | B[128][32], 16 KB
  const int t = threadIdx.x;
  const int bm = blockIdx.x, bn = blockIdx.y;
  const int lane = t & 63, w = t >> 6;
  const int hi = lane >> 4, l15 = lane & 15;

  const unsigned short* Wp; long wbase;
  if (bn < 16)       { Wp = Wq; wbase = (long)bn * 128; }
  else if (bn == 16) { Wp = Wk; wbase = 0; }
  else               { Wp = Wv; wbase = 0; }

  f32x4 acc[2][8] = {};

  for (int k0 = 0; k0 < 2048; k0 += 32) {
    #pragma unroll
    for (int i = 0; i < 2; ++i) {
      int c = w + 4 * i;
      gl2l(A + (long)(bm * 128 + 16 * c + (lane >> 2)) * 2048 + k0 + (lane & 3) * 8,
           &lds[c * 512]);
      gl2l(Wp + (wbase + 16 * c + (lane >> 2)) * 2048 + k0 + (lane & 3) * 8,
           &lds[4096 + c * 512]);
    }
    __syncthreads();
    bf16x8 af[2], bff[8];
    #pragma unroll
    for (int m = 0; m < 2; ++m)
      af[m] = *reinterpret_cast<const bf16x8*>(&lds[(w * 32 + m * 16 + l15) * 32 + hi * 8]);
    #pragma unroll
    for (int n = 0; n < 8; ++n)
      bff[n] = *reinterpret_cast<const bf16x8*>(&lds[4096 + (n * 16 + l15) * 32 + hi * 8]);
    #pragma unroll
    for (int m = 0; m < 2; ++m)
      #pragma unroll
      for (int n = 0; n < 8; ++n)
        acc[m][n] = mfma16(af[m], bff[n], acc[m][n]);
    __syncthreads();
  }

  const int rowbase = bm * 128 + w * 32;
  if (bn == 17) {
    #pragma unroll
    for (int m = 0; m < 2; ++m)
      #pragma unroll
      for (int r = 0; r < 4; ++r) {
        int grow = rowbase + m * 16 + hi * 4 + r;
        int b = grow >> 11, s = grow & 2047;
        long base = ((long)b * cS + s) * cD;
        #pragma unroll
        for (int n = 0; n < 8; ++n)
          Vn[base + n * 16 + l15] = f2bf(acc[m][n][r]);
      }
  } else {
    #pragma unroll
    for (int m = 0; m < 2; ++m)
      #pragma unroll
      for (int r = 0; r < 4; ++r) {
        int grow = rowbase + m * 16 + hi * 4 + r;
        int b = grow >> 11, s = grow & 2047;
        float o1[4], o2[4], ss = 0.f;
        #pragma unroll
        for (int n = 0; n < 4; ++n) {
          float cv = cosb[(long)s * 64 + n * 16 + l15];
          float sv = sinb[(long)s * 64 + n * 16 + l15];
          float x1 = acc[m][n][r], x2 = acc[m][n + 4][r];
          o1[n] = x1 * cv + x2 * sv;
          o2[n] = x2 * cv - x1 * sv;
          ss += o1[n] * o1[n] + o2[n] * o2[n];
        }
        ss += __shfl_xor(ss, 1); ss += __shfl_xor(ss, 2);
        ss += __shfl_xor(ss, 4); ss += __shfl_xor(ss, 8);
        float scn = rsqrtf(ss * (1.0f / 128.0f) + cEPS);
        if (bn < 16) {
          float sq = scn * cQS;                 // fold softmax scale into Q
          long base = (((long)b * cH + bn) * cS + s) * cD;
          #pragma unroll
          for (int n = 0; n < 4; ++n) {
            Qn[base + n * 16 + l15] = f2bf(o1[n] * sq);
            Qn[base + 64 + n * 16 + l15] = f2bf(o2[n] * sq);
          }
        } else {
          long base = ((long)b * cS + s) * cD;
          int xs = (s & 7) << 3;
          #pragma unroll
          for (int n = 0; n < 4; ++n) {
            Kn[base + ((n * 16 + l15) ^ xs)] = f2bf(o1[n] * scn);
            Kn[base + (((64 + n * 16 + l15)) ^ xs)] = f2bf(o2[n] * scn);
          }
        }
      }
  }
}

// -------- V transpose: Vn[b][s][d] -> Vt[b][d][s ^ ((d&7)<<3)] --------
__global__ __launch_bounds__(256) void vtrans(
    const unsigned short* __restrict__ Vn, unsigned short* __restrict__ Vt)
{
  __shared__ unsigned short Tl[64][72];
  const int t = threadIdx.x;
  const int st = blockIdx.x * 64, dt = blockIdx.y * 64, b = blockIdx.z;
  const unsigned short* Vb = Vn + (long)b * cS * cD;
  #pragma unroll
  for (int i = 0; i < 2; ++i) {
    int r = i * 32 + (t >> 3), c8 = (t & 7) * 8;
    *reinterpret_cast<uint4*>(&Tl[r][c8]) =
        *reinterpret_cast<const uint4*>(&Vb[(long)(st + r) * cD + dt + c8]);
  }
  __syncthreads();
  unsigned short* Vo = Vt + (long)b * cD * cS;
  #pragma unroll
  for (int i = 0; i < 2; ++i) {
    int d = i * 32 + (t >> 3), sb = (t & 7) * 8;
    unsigned short e[8];
    #pragma unroll
    for (int j = 0; j < 8; ++j) e[j] = Tl[sb + j][d];
    uint4 o;
    o.x = (unsigned)e[0] | ((unsigned)e[1] << 16);
    o.y = (unsigned)e[2] | ((unsigned)e[3] << 16);
    o.z = (unsigned)e[4] | ((unsigned)e[5] << 16);
    o.w = (unsigned)e[6] | ((unsigned)e[7] << 16);
    int dg = dt + d;
    *reinterpret_cast<uint4*>(&Vo[(long)dg * cS + st + (sb ^ ((dg & 7) << 3))]) = o;
  }
}

// -------- Flash attention: QBLK=32/wave, IN-BLOCK fold --------
// Waves 0-1 own qtile bx (rows 0-31 / 32-63); waves 2-3 own qtile 31-bx.
// Single kv loop to nt = 32-bx; waves 0-1 skip compute (not barriers) for
// kt > bx. Halves per-CU LDS frag redundancy vs QBLK=16 (frag addrs are
// lane-only); staging/barriers -26%; heavy blocks (bx=0) dispatch first.
__global__ __launch_bounds__(256) void attn2(
    const unsigned short* __restrict__ Qn,   // pre-scaled by cQS
    const unsigned short* __restrict__ Kn,   // swizzled
    const unsigned short* __restrict__ Vt,   // [b][d][s] swizzled
    unsigned short* __restrict__ O)          // [B*S][H*D] bf16
{
  __shared__ unsigned short lds[32768];      // K[2][64][128] | V[2][128][64]
  const int t = threadIdx.x, w = t >> 6, lane = t & 63;
  const int hi = lane >> 4, l15 = lane & 15;
  const int h = blockIdx.y, b = blockIdx.z;
  const unsigned short* Qb = Qn + (long)(b * cH + h) * cS * cD;
  const unsigned short* Kb = Kn + (long)b * cS * cD;
  const unsigned short* Vtb = Vt + (long)b * cD * cS;
  const int x3 = (l15 & 7) << 3;             // frag-read XOR (us units)

  union O4 { unsigned u[2]; bf16x4 v; };
  O4 o4; o4.u[0] = o4.u[1] = 0x3F803F80u;
  const bf16x4 ones4 = o4.v;                 // bf16 1.0 x4

  const int bx = blockIdx.x;
  const bool lo = (w < 2);                   // wave pair 0-1 -> light qtile
  const int qtLo = bx, qtHi = 31 - bx;
  const int myqt = lo ? qtLo : qtHi;
  const int nt = qtHi + 1;                   // kv tiles staged (32-bx)
  const int q0 = myqt * 64 + (w & 1) * 32;   // this wave's 32-row q base
  const int qrowA = q0 + l15;
  const int qrowB = q0 + 16 + l15;

  bf16x8 qfA[4], qfB[4];
  #pragma unroll
  for (int kc = 0; kc < 4; ++kc) {
    qfA[kc] = *reinterpret_cast<const bf16x8*>(&Qb[(long)qrowA * cD + kc * 32 + hi * 8]);
    qfB[kc] = *reinterpret_cast<const bf16x8*>(&Qb[(long)qrowB * cD + kc * 32 + hi * 8]);
  }

  // per-thread running source pointers (all waves stage their quarter)
  const unsigned short* kp = Kb + (long)(16 * w + (lane >> 4)) * cD + (lane & 15) * 8;
  const unsigned short* vp[4];
  #pragma unroll
  for (int i = 0; i < 4; ++i)
    vp[i] = Vtb + (long)(32 * w + 8 * i + (lane >> 3)) * cS + (lane & 7) * 8;

  auto STAGE = [&](int buf) {
    unsigned short* kd = &lds[buf * 8192 + w * 2048];
    unsigned short* vd = &lds[16384 + buf * 8192 + w * 2048];
    #pragma unroll
    for (int i = 0; i < 4; ++i) {
      gl2l(kp + i * 512, kd + i * 512);
      gl2l(vp[i], vd + i * 512);
    }
    kp += 8192;
    #pragma unroll
    for (int i = 0; i < 4; ++i) vp[i] += 64;
  };

  f32x4 oaccA[8] = {}, oaccB[8] = {};
  f32x4 laccA = {}, laccB = {};
  float mrunA = -1e30f, mrunB = -1e30f;

  STAGE(0);
  int cur = 0;

  // per-half softmax: st -> paOut (out-param; NEVER return local array — R9 bug)
  auto SOFTMAX = [&](f32x4 (&st)[4], float& mrun, f32x4& lacc, f32x4 (&oacc)[8],
                     bf16x4 (&paOut)[4], int qrow, int kv0, bool domask) {
    float p[4][4];
    if (domask) {
      #pragma unroll
      for (int n = 0; n < 4; ++n)
        #pragma unroll
        for (int r = 0; r < 4; ++r) {
          int kv = kv0 + n * 16 + hi * 4 + r;
          p[n][r] = (kv <= qrow) ? st[n][r] : -1e30f;
        }
    } else {
      #pragma unroll
      for (int n = 0; n < 4; ++n)
        #pragma unroll
        for (int r = 0; r < 4; ++r)
          p[n][r] = st[n][r];
    }
    float t0 = fmaxf(fmaxf(p[0][0], p[0][1]), fmaxf(p[0][2], p[0][3]));
    float t1 = fmaxf(fmaxf(p[1][0], p[1][1]), fmaxf(p[1][2], p[1][3]));
    float t2 = fmaxf(fmaxf(p[2][0], p[2][1]), fmaxf(p[2][2], p[2][3]));
    float t3 = fmaxf(fmaxf(p[3][0], p[3][1]), fmaxf(p[3][2], p[3][3]));
    float pmax = fmaxf(fmaxf(t0, t1), fmaxf(t2, t3));
    if (!__all(pmax - mrun <= 8.0f)) {
      pmax = fmaxf(pmax, __shfl_xor(pmax, 16));
      pmax = fmaxf(pmax, __shfl_xor(pmax, 32));
      float mnew = fmaxf(mrun, pmax);
      float alpha = exp2f(mrun - mnew);
      mrun = mnew;
      #pragma unroll
      for (int n = 0; n < 8; ++n)
        #pragma unroll
        for (int r = 0; r < 4; ++r) oacc[n][r] *= alpha;
      #pragma unroll
      for (int r = 0; r < 4; ++r) lacc[r] *= alpha;
    }
    #pragma unroll
    for (int n = 0; n < 4; ++n)
      #pragma unroll
      for (int r = 0; r < 4; ++r)
        p[n][r] = exp2f(p[n][r] - mrun);
    #pragma unroll
    for (int n = 0; n < 4; ++n) {
      O4 pu;
      pu.u[0] = cvtpk(p[n][0], p[n][1]);
      pu.u[1] = cvtpk(p[n][2], p[n][3]);
      paOut[n] = pu.v;
    }
  };

  #pragma unroll 1
  for (int kt = 0; kt < nt; ++kt) {
    const int kv0 = kt * 64;
    asm volatile("s_waitcnt vmcnt(0)" ::: "memory");
    __builtin_amdgcn_s_barrier();
    __builtin_amdgcn_sched_barrier(0);
    if (kt + 1 < nt) STAGE(cur ^ 1);

    const bool active = (!lo) || (kt <= qtLo);
    if (active) {
      const unsigned short* kbase = &lds[cur * 8192];
      const unsigned short* vbase = &lds[16384 + cur * 8192];

      // QK^T both halves, sharing each kf read
      f32x4 stA[4] = {}, stB[4] = {};
      __builtin_amdgcn_s_setprio(1);
      #pragma unroll
      for (int kc = 0; kc < 4; ++kc) {
        #pragma unroll
        for (int n = 0; n < 4; ++n) {
          bf16x8 kf = *reinterpret_cast<const bf16x8*>(
              &kbase[(n * 16 + l15) * 128 + ((kc * 32 + hi * 8) ^ x3)]);
          stA[n] = mfma16(kf, qfA[kc], stA[n]);
          stB[n] = mfma16(kf, qfB[kc], stB[n]);
        }
      }
      __builtin_amdgcn_s_setprio(0);

      const bool domask = (kt == myqt);
      bf16x4 paA[4], paB[4];
      SOFTMAX(stA, mrunA, laccA, oaccA, paA, qrowA, kv0, domask);
      SOFTMAX(stB, mrunB, laccB, oaccB, paB, qrowB, kv0, domask);

      // PV both halves, sharing each vf read; lacc via ones-row
      __builtin_amdgcn_s_setprio(1);
      #pragma unroll
      for (int n = 0; n < 4; ++n) {
        laccA = mfma16k16(ones4, paA[n], laccA);
        laccB = mfma16k16(ones4, paB[n], laccB);
      }
      #pragma unroll
      for (int n2 = 0; n2 < 8; ++n2) {
        #pragma unroll
        for (int n = 0; n < 4; ++n) {
          bf16x4 vf = *reinterpret_cast<const bf16x4*>(
              &vbase[(n2 * 16 + l15) * 64 + ((n * 16 + hi * 4) ^ x3)]);
          oaccA[n2] = mfma16k16(vf, paA[n], oaccA[n2]);
          oaccB[n2] = mfma16k16(vf, paB[n], oaccB[n2]);
        }
      }
      __builtin_amdgcn_s_setprio(0);
    }
    cur ^= 1;
  }

  // separate last compute from epilogue LDS overwrite (Ol aliases K buffers)
  __builtin_amdgcn_s_barrier();

  // epilogue: both halves via per-wave LDS transpose, coalesced store
  #pragma unroll
  for (int half = 0; half < 2; ++half) {
    f32x4& lacc = half ? laccB : laccA;
    f32x4* oacc = half ? oaccB : oaccA;
    float inv = 1.0f / lacc[0];
    int qb = q0 + half * 16;
    unsigned short* Ol = &lds[w * 2176];   // [16][136]
    #pragma unroll
    for (int n2 = 0; n2 < 8; ++n2)
      #pragma unroll
      for (int r = 0; r < 4; ++r)
        Ol[l15 * 136 + n2 * 16 + hi * 4 + r] = f2bf(oacc[n2][r] * inv);
    __syncthreads();
    #pragma unroll
    for (int i = 0; i < 4; ++i) {
      int row = hi + 4 * i;
      uint4 ov = *reinterpret_cast<const uint4*>(&Ol[row * 136 + l15 * 8]);
      *reinterpret_cast<uint4*>(
          &O[(long)(b * cS + qb + row) * (cH * cD) + h * cD + l15 * 8]) = ov;
    }
    __syncthreads();
  }
}

// -------- output GEMM (m97 structure), fp32 C --------
__global__ __launch_bounds__(256) void gemm_out(
    const unsigned short* __restrict__ A,    // Ob [4096][2048]
    const unsigned short* __restrict__ W,    // wob [2048][2048]
    float* __restrict__ C)
{
  __shared__ unsigned short lds[8192];
  const int t = threadIdx.x;
  const int bm = blockIdx.x, bn = blockIdx.y;
  const int lane = t & 63, w = t >> 6;
  const int wr = w >> 1, wc = w & 1, hi = lane >> 4, l15 = lane & 15;
  const long wbase = (long)bn * 128;

  f32x4 acc[4][4] = {};
  for (int k0 = 0; k0 < 2048; k0 += 32) {
    #pragma unroll
    for (int i = 0; i < 2; ++i) {
      int c = w + 4 * i;
      gl2l(A + (long)(bm * 128 + 16 * c + (lane >> 2)) * 2048 + k0 + (lane & 3) * 8,
           &lds[c * 512]);
      gl2l(W + (wbase + 16 * c + (lane >> 2)) * 2048 + k0 + (lane & 3) * 8,
           &lds[4096 + c * 512]);
    }
    __syncthreads();
    bf16x8 af[4], bff[4];
    #pragma unroll
    for (int m = 0; m < 4; ++m)
      af[m] = *reinterpret_cast<const bf16x8*>(&lds[(wr * 64 + m * 16 + l15) * 32 + hi * 8]);
    #pragma unroll
    for (int n = 0; n < 4; ++n)
      bff[n] = *reinterpret_cast<const bf16x8*>(&lds[4096 + (wc * 64 + n * 16 + l15) * 32 + hi * 8]);
    #pragma unroll
    for (int m = 0; m < 4; ++m)
      #pragma unroll
      for (int n = 0; n < 4; ++n)
        acc[m][n] = mfma16(af[m], bff[n], acc[m][n]);
    __syncthreads();
  }

  #pragma unroll
  for (int m = 0; m < 4; ++m) {
    int row = bm * 128 + wr * 64 + m * 16 + hi * 4;
    #pragma unroll
    for (int n = 0; n < 4; ++n) {
      int col = bn * 128 + wc * 64 + n * 16 + l15;
      #pragma unroll
      for (int r = 0; r < 4; ++r)
        C[(long)(row + r) * 2048 + col] = acc[m][n][r];
    }
  }
}

extern "C" void kernel_launch(void* const* d_in, const int* in_sizes, int n_in,
                              void* d_out, int out_size, void* d_ws, size_t ws_size,
                              hipStream_t stream) {
  const float* x    = (const float*)d_in[0];
  const float* cosb = (const float*)d_in[1];
  const float* sinb = (const float*)d_in[2];
  const float* wq   = (const float*)d_in[3];
  const float* wk   = (const float*)d_in[4];
  const float* wv   = (const float*)d_in[5];
  const float* wo   = (const float*)d_in[6];
  float* out = (float*)d_out;

  char* ws = (char*)d_ws;
  unsigned short* xb  = (unsigned short*)(ws);                 // 16,777,216 B
  unsigned short* wqb = (unsigned short*)(ws + 16777216);      //  8,388,608 B
  unsigned short* wkb = (unsigned short*)(ws + 25165824);      //    524,288 B
  unsigned short* wvb = (unsigned short*)(ws + 25690112);      //    524,288 B
  unsigned short* Qn  = (unsigned short*)(ws + 26214400);      // 16,777,216 B
  unsigned short* Kn  = (unsigned short*)(ws + 42991616);      //  1,048,576 B
  unsigned short* Vn  = (unsigned short*)(ws + 44040192);      //  1,048,576 B
  unsigned short* Vtg = (unsigned short*)(ws + 45088768);      //  1,048,576 B
  unsigned short* wob = (unsigned short*)(ws + 46137344);      //  8,388,608 B
  unsigned short* Ob  = (unsigned short*)ws;                   // alias xb (dead)

  cvt_all<<<dim3(8448), 256, 0, stream>>>(x, wq, wk, wv, wo, xb, wqb, wkb, wvb, wob);
  gemm_qkv<<<dim3(32, 18), 256, 0, stream>>>(xb, wqb, wkb, wvb, cosb, sinb, Qn, Kn, Vn);
  vtrans<<<dim3(32, 2, 2), 256, 0, stream>>>(Vn, Vtg);
  attn2<<<dim3(16, 16, 2), 256, 0, stream>>>(Qn, Kn, Vtg, Ob);
  gemm_out<<<dim3(32, 16), 256, 0, stream>>>(Ob, wob, out);
}

// Round 16
// 203.756 us; speedup vs baseline: 1.3608x; 1.3608x over previous
//
#include <hip/hip_runtime.h>
#include <hip/hip_bf16.h>

typedef __attribute__((ext_vector_type(8))) short bf16x8;
typedef __attribute__((ext_vector_type(4))) short bf16x4;
typedef __attribute__((ext_vector_type(4))) float f32x4;

constexpr int cH = 16, cD = 128, cHID = 2048, cS = 2048, cB = 2;
constexpr float cEPS = 1.1920928955078125e-07f;
constexpr float cQS = 0.08838834764831845f * 1.442695040888963f; // 1/sqrt(D)*log2(e)

// manual RNE fp32->bf16 (3 VALU ops; __float2bfloat16 does NOT inline well — R6 regression)
__device__ __forceinline__ unsigned short f2bf(float f) {
  union { float f; unsigned u; } v; v.f = f;
  unsigned r = v.u + 0x7fffu + ((v.u >> 16) & 1u);
  return (unsigned short)(r >> 16);
}
__device__ __forceinline__ unsigned pk2(float a, float b) {
  return (unsigned)f2bf(a) | ((unsigned)f2bf(b) << 16);
}
__device__ __forceinline__ unsigned cvtpk(float a, float b) {
  unsigned r;
  asm("v_cvt_pk_bf16_f32 %0, %1, %2" : "=v"(r) : "v"(a), "v"(b));
  return r;
}
__device__ __forceinline__ f32x4 mfma16(bf16x8 a, bf16x8 b, f32x4 c) {
  return __builtin_amdgcn_mfma_f32_16x16x32_bf16(a, b, c, 0, 0, 0);
}
__device__ __forceinline__ f32x4 mfma16k16(bf16x4 a, bf16x4 b, f32x4 c) {
#if __has_builtin(__builtin_amdgcn_mfma_f32_16x16x16bf16_1k)
  return __builtin_amdgcn_mfma_f32_16x16x16bf16_1k(a, b, c, 0, 0, 0);
#else
  f32x4 d;
  asm volatile("v_mfma_f32_16x16x16_bf16 %0, %1, %2, %3\n\ts_nop 7\n\ts_nop 2"
               : "=v"(d) : "v"(a), "v"(b), "v"(c));
  return d;
#endif
}
// async global->LDS, 16B per lane; lds ptr must be wave-uniform base.
__device__ __forceinline__ void gl2l(const void* g, void* l) {
  __builtin_amdgcn_global_load_lds(
      (const __attribute__((address_space(1))) unsigned int*)g,
      (__attribute__((address_space(3))) unsigned int*)l, 16, 0, 0);
}

// -------- cvt fp32 -> bf16 (x, wq, wk, wv, wo concatenated) --------
__global__ __launch_bounds__(256) void cvt_all(
    const float* __restrict__ x, const float* __restrict__ wq,
    const float* __restrict__ wk, const float* __restrict__ wv,
    const float* __restrict__ wo,
    unsigned short* __restrict__ xb, unsigned short* __restrict__ wqb,
    unsigned short* __restrict__ wkb, unsigned short* __restrict__ wvb,
    unsigned short* __restrict__ wob)
{
  long i = (long)blockIdx.x * 2048 + threadIdx.x * 8;
  const float* s; unsigned short* d; long off;
  if (i < 8388608)       { s = x;  d = xb;  off = i; }
  else if (i < 12582912) { s = wq; d = wqb; off = i - 8388608; }
  else if (i < 12845056) { s = wk; d = wkb; off = i - 12582912; }
  else if (i < 13107200) { s = wv; d = wvb; off = i - 12845056; }
  else                   { s = wo; d = wob; off = i - 13107200; }
  float4 v0 = *reinterpret_cast<const float4*>(s + off);
  float4 v1 = *reinterpret_cast<const float4*>(s + off + 4);
  uint4 o; o.x = pk2(v0.x, v0.y); o.y = pk2(v0.z, v0.w);
  o.z = pk2(v1.x, v1.y); o.w = pk2(v1.z, v1.w);
  *reinterpret_cast<uint4*>(d + off) = o;
}

// -------- QKV GEMM (m97 structure) + register RoPE/RMSNorm epilogue --------
__global__ __launch_bounds__(256) void gemm_qkv(
    const unsigned short* __restrict__ A,    // xb [4096][2048]
    const unsigned short* __restrict__ Wq,   // [2048][2048]
    const unsigned short* __restrict__ Wk,   // [128][2048]
    const unsigned short* __restrict__ Wv,   // [128][2048]
    const float* __restrict__ cosb, const float* __restrict__ sinb,
    unsigned short* __restrict__ Qn,         // [B][H][S][D]
    unsigned short* __restrict__ Kn,         // [B][S][D] swizzled
    unsigned short* __restrict__ Vn)         // [B][S][D]
{
  __shared__ unsigned short lds[8192];       // A[128][32] | B[128][32], 16 KB
  const int t = threadIdx.x;
  const int bm = blockIdx.x, bn = blockIdx.y;
  const int lane = t & 63, w = t >> 6;
  const int hi = lane >> 4, l15 = lane & 15;

  const unsigned short* Wp; long wbase;
  if (bn < 16)       { Wp = Wq; wbase = (long)bn * 128; }
  else if (bn == 16) { Wp = Wk; wbase = 0; }
  else               { Wp = Wv; wbase = 0; }

  f32x4 acc[2][8] = {};

  for (int k0 = 0; k0 < 2048; k0 += 32) {
    #pragma unroll
    for (int i = 0; i < 2; ++i) {
      int c = w + 4 * i;
      gl2l(A + (long)(bm * 128 + 16 * c + (lane >> 2)) * 2048 + k0 + (lane & 3) * 8,
           &lds[c * 512]);
      gl2l(Wp + (wbase + 16 * c + (lane >> 2)) * 2048 + k0 + (lane & 3) * 8,
           &lds[4096 + c * 512]);
    }
    __syncthreads();
    bf16x8 af[2], bff[8];
    #pragma unroll
    for (int m = 0; m < 2; ++m)
      af[m] = *reinterpret_cast<const bf16x8*>(&lds[(w * 32 + m * 16 + l15) * 32 + hi * 8]);
    #pragma unroll
    for (int n = 0; n < 8; ++n)
      bff[n] = *reinterpret_cast<const bf16x8*>(&lds[4096 + (n * 16 + l15) * 32 + hi * 8]);
    #pragma unroll
    for (int m = 0; m < 2; ++m)
      #pragma unroll
      for (int n = 0; n < 8; ++n)
        acc[m][n] = mfma16(af[m], bff[n], acc[m][n]);
    __syncthreads();
  }

  const int rowbase = bm * 128 + w * 32;
  if (bn == 17) {
    #pragma unroll
    for (int m = 0; m < 2; ++m)
      #pragma unroll
      for (int r = 0; r < 4; ++r) {
        int grow = rowbase + m * 16 + hi * 4 + r;
        int b = grow >> 11, s = grow & 2047;
        long base = ((long)b * cS + s) * cD;
        #pragma unroll
        for (int n = 0; n < 8; ++n)
          Vn[base + n * 16 + l15] = f2bf(acc[m][n][r]);
      }
  } else {
    #pragma unroll
    for (int m = 0; m < 2; ++m)
      #pragma unroll
      for (int r = 0; r < 4; ++r) {
        int grow = rowbase + m * 16 + hi * 4 + r;
        int b = grow >> 11, s = grow & 2047;
        float o1[4], o2[4], ss = 0.f;
        #pragma unroll
        for (int n = 0; n < 4; ++n) {
          float cv = cosb[(long)s * 64 + n * 16 + l15];
          float sv = sinb[(long)s * 64 + n * 16 + l15];
          float x1 = acc[m][n][r], x2 = acc[m][n + 4][r];
          o1[n] = x1 * cv + x2 * sv;
          o2[n] = x2 * cv - x1 * sv;
          ss += o1[n] * o1[n] + o2[n] * o2[n];
        }
        ss += __shfl_xor(ss, 1); ss += __shfl_xor(ss, 2);
        ss += __shfl_xor(ss, 4); ss += __shfl_xor(ss, 8);
        float scn = rsqrtf(ss * (1.0f / 128.0f) + cEPS);
        if (bn < 16) {
          float sq = scn * cQS;                 // fold softmax scale into Q
          long base = (((long)b * cH + bn) * cS + s) * cD;
          #pragma unroll
          for (int n = 0; n < 4; ++n) {
            Qn[base + n * 16 + l15] = f2bf(o1[n] * sq);
            Qn[base + 64 + n * 16 + l15] = f2bf(o2[n] * sq);
          }
        } else {
          long base = ((long)b * cS + s) * cD;
          int xs = (s & 7) << 3;
          #pragma unroll
          for (int n = 0; n < 4; ++n) {
            Kn[base + ((n * 16 + l15) ^ xs)] = f2bf(o1[n] * scn);
            Kn[base + (((64 + n * 16 + l15)) ^ xs)] = f2bf(o2[n] * scn);
          }
        }
      }
  }
}

// -------- V transpose: Vn[b][s][d] -> Vt[b][d][s ^ ((d&7)<<3)] --------
__global__ __launch_bounds__(256) void vtrans(
    const unsigned short* __restrict__ Vn, unsigned short* __restrict__ Vt)
{
  __shared__ unsigned short Tl[64][72];
  const int t = threadIdx.x;
  const int st = blockIdx.x * 64, dt = blockIdx.y * 64, b = blockIdx.z;
  const unsigned short* Vb = Vn + (long)b * cS * cD;
  #pragma unroll
  for (int i = 0; i < 2; ++i) {
    int r = i * 32 + (t >> 3), c8 = (t & 7) * 8;
    *reinterpret_cast<uint4*>(&Tl[r][c8]) =
        *reinterpret_cast<const uint4*>(&Vb[(long)(st + r) * cD + dt + c8]);
  }
  __syncthreads();
  unsigned short* Vo = Vt + (long)b * cD * cS;
  #pragma unroll
  for (int i = 0; i < 2; ++i) {
    int d = i * 32 + (t >> 3), sb = (t & 7) * 8;
    unsigned short e[8];
    #pragma unroll
    for (int j = 0; j < 8; ++j) e[j] = Tl[sb + j][d];
    uint4 o;
    o.x = (unsigned)e[0] | ((unsigned)e[1] << 16);
    o.y = (unsigned)e[2] | ((unsigned)e[3] << 16);
    o.z = (unsigned)e[4] | ((unsigned)e[5] << 16);
    o.w = (unsigned)e[6] | ((unsigned)e[7] << 16);
    int dg = dt + d;
    *reinterpret_cast<uint4*>(&Vo[(long)dg * cS + st + (sb ^ ((dg & 7) << 3))]) = o;
  }
}

// -------- Flash attention (R8 structure, single barrier per kv-tile) --------
// Folded-uniform grid: block bx does q-tiles bx and 31-bx (33 tiles total).
// T3 2-phase rotation: {vmcnt(0); barrier; STAGE(next->other buf); compute}.
// Safe: at the barrier all waves finished reading the buffer STAGE overwrites,
// and own-vmcnt(0) + barrier jointly guarantee all staged loads landed.
__global__ __launch_bounds__(256) void attn2(
    const unsigned short* __restrict__ Qn,   // pre-scaled by cQS
    const unsigned short* __restrict__ Kn,   // swizzled
    const unsigned short* __restrict__ Vt,   // [b][d][s] swizzled
    unsigned short* __restrict__ O)          // [B*S][H*D] bf16
{
  __shared__ unsigned short lds[32768];      // K[2][64][128] | V[2][128][64]
  const int t = threadIdx.x, w = t >> 6, lane = t & 63;
  const int hi = lane >> 4, l15 = lane & 15;
  const int h = blockIdx.y, b = blockIdx.z;
  const unsigned short* Qb = Qn + (long)(b * cH + h) * cS * cD;
  const unsigned short* Kb = Kn + (long)b * cS * cD;
  const unsigned short* Vtb = Vt + (long)b * cD * cS;
  const int x3 = (l15 & 7) << 3;             // frag-read XOR (us units)

  union O4 { unsigned u[2]; bf16x4 v; };
  O4 o4; o4.u[0] = o4.u[1] = 0x3F803F80u;
  const bf16x4 ones4 = o4.v;                 // bf16 1.0 x4

  #pragma unroll 1
  for (int pass = 0; pass < 2; ++pass) {
    const int qt = (pass == 0) ? blockIdx.x : 31 - blockIdx.x;
    const int q0 = qt * 64;
    const int qrow = q0 + w * 16 + l15;
    const int nt = qt + 1;

    bf16x8 qf[4];
    #pragma unroll
    for (int kc = 0; kc < 4; ++kc)
      qf[kc] = *reinterpret_cast<const bf16x8*>(&Qb[(long)qrow * cD + kc * 32 + hi * 8]);

    // per-thread running source pointers
    const unsigned short* kp = Kb + (long)(16 * w + (lane >> 4)) * cD + (lane & 15) * 8;
    const unsigned short* vp[4];
    #pragma unroll
    for (int i = 0; i < 4; ++i)
      vp[i] = Vtb + (long)(32 * w + 8 * i + (lane >> 3)) * cS + (lane & 7) * 8;

    auto STAGE = [&](int buf) {
      unsigned short* kd = &lds[buf * 8192 + w * 2048];
      unsigned short* vd = &lds[16384 + buf * 8192 + w * 2048];
      #pragma unroll
      for (int i = 0; i < 4; ++i) {
        gl2l(kp + i * 512, kd + i * 512);
        gl2l(vp[i], vd + i * 512);
      }
      kp += 8192;                                  // advance 64 kv rows
      #pragma unroll
      for (int i = 0; i < 4; ++i) vp[i] += 64;     // advance 64 kv cols
    };

    f32x4 oacc[8] = {};
    f32x4 lacc = {};
    float mrun = -1e30f;

    STAGE(0);
    int cur = 0;

    #pragma unroll 1
    for (int kt = 0; kt < nt; ++kt) {
      const int kv0 = kt * 64;
      // single barrier per tile: wait own staged loads, sync, then issue next
      asm volatile("s_waitcnt vmcnt(0)" ::: "memory");
      __builtin_amdgcn_s_barrier();
      __builtin_amdgcn_sched_barrier(0);
      if (kt + 1 < nt) STAGE(cur ^ 1);   // other buffer; readers done at barrier

      const unsigned short* kbase = &lds[cur * 8192];
      const unsigned short* vbase = &lds[16384 + cur * 8192];

      // QK^T swapped: st[n][r] = S^T[kv = n*16 + hi*4 + r][q]  (log2-scaled)
      f32x4 st[4] = {};
      __builtin_amdgcn_s_setprio(1);
      #pragma unroll
      for (int kc = 0; kc < 4; ++kc) {
        #pragma unroll
        for (int n = 0; n < 4; ++n) {
          bf16x8 kf = *reinterpret_cast<const bf16x8*>(
              &kbase[(n * 16 + l15) * 128 + ((kc * 32 + hi * 8) ^ x3)]);
          st[n] = mfma16(kf, qf[kc], st[n]);
        }
      }
      __builtin_amdgcn_s_setprio(0);

      float p[4][4];
      if (kt == qt) {
        #pragma unroll
        for (int n = 0; n < 4; ++n)
          #pragma unroll
          for (int r = 0; r < 4; ++r) {
            int kv = kv0 + n * 16 + hi * 4 + r;
            p[n][r] = (kv <= qrow) ? st[n][r] : -1e30f;
          }
      } else {
        #pragma unroll
        for (int n = 0; n < 4; ++n)
          #pragma unroll
          for (int r = 0; r < 4; ++r)
            p[n][r] = st[n][r];
      }

      // per-lane tree max; cross-lane reduce ONLY on defer violation (T13)
      float t0 = fmaxf(fmaxf(p[0][0], p[0][1]), fmaxf(p[0][2], p[0][3]));
      float t1 = fmaxf(fmaxf(p[1][0], p[1][1]), fmaxf(p[1][2], p[1][3]));
      float t2 = fmaxf(fmaxf(p[2][0], p[2][1]), fmaxf(p[2][2], p[2][3]));
      float t3 = fmaxf(fmaxf(p[3][0], p[3][1]), fmaxf(p[3][2], p[3][3]));
      float pmax = fmaxf(fmaxf(t0, t1), fmaxf(t2, t3));

      if (!__all(pmax - mrun <= 8.0f)) {
        pmax = fmaxf(pmax, __shfl_xor(pmax, 16));
        pmax = fmaxf(pmax, __shfl_xor(pmax, 32));
        float mnew = fmaxf(mrun, pmax);
        float alpha = exp2f(mrun - mnew);
        mrun = mnew;
        #pragma unroll
        for (int n = 0; n < 8; ++n)
          #pragma unroll
          for (int r = 0; r < 4; ++r) oacc[n][r] *= alpha;
        #pragma unroll
        for (int r = 0; r < 4; ++r) lacc[r] *= alpha;
      }

      #pragma unroll
      for (int n = 0; n < 4; ++n)
        #pragma unroll
        for (int r = 0; r < 4; ++r)
          p[n][r] = exp2f(p[n][r] - mrun);

      // P -> PV B-fragment directly (16x16x16 layout match), via v_cvt_pk
      bf16x4 paB[4];
      #pragma unroll
      for (int n = 0; n < 4; ++n) {
        O4 pu;
        pu.u[0] = cvtpk(p[n][0], p[n][1]);
        pu.u[1] = cvtpk(p[n][2], p[n][3]);
        paB[n] = pu.v;
      }

      // PV: oacc[n2][r] = O^T[d = n2*16 + hi*4 + r][q]; lacc via ones-row
      __builtin_amdgcn_s_setprio(1);
      #pragma unroll
      for (int n = 0; n < 4; ++n) lacc = mfma16k16(ones4, paB[n], lacc);
      #pragma unroll
      for (int n2 = 0; n2 < 8; ++n2) {
        #pragma unroll
        for (int n = 0; n < 4; ++n) {
          bf16x4 vf = *reinterpret_cast<const bf16x4*>(
              &vbase[(n2 * 16 + l15) * 64 + ((n * 16 + hi * 4) ^ x3)]);
          oacc[n2] = mfma16k16(vf, paB[n], oacc[n2]);
        }
      }
      __builtin_amdgcn_s_setprio(0);
      cur ^= 1;
    }

    // separate last compute from epilogue LDS overwrite (Ol aliases K buffers)
    __builtin_amdgcn_s_barrier();

    // epilogue: O^T -> O via per-wave LDS transpose, coalesced store
    {
      float inv = 1.0f / lacc[0];
      unsigned short* Ol = &lds[w * 2176];   // [16][136]
      #pragma unroll
      for (int n2 = 0; n2 < 8; ++n2)
        #pragma unroll
        for (int r = 0; r < 4; ++r)
          Ol[l15 * 136 + n2 * 16 + hi * 4 + r] = f2bf(oacc[n2][r] * inv);
      __syncthreads();
      #pragma unroll
      for (int i = 0; i < 4; ++i) {
        int row = hi + 4 * i;
        uint4 ov = *reinterpret_cast<const uint4*>(&Ol[row * 136 + l15 * 8]);
        *reinterpret_cast<uint4*>(
            &O[(long)(b * cS + q0 + w * 16 + row) * (cH * cD) + h * cD + l15 * 8]) = ov;
      }
      __syncthreads();                 // before next pass restages LDS
    }
  }
}

// -------- output GEMM (m97 structure), fp32 C --------
__global__ __launch_bounds__(256) void gemm_out(
    const unsigned short* __restrict__ A,    // Ob [4096][2048]
    const unsigned short* __restrict__ W,    // wob [2048][2048]
    float* __restrict__ C)
{
  __shared__ unsigned short lds[8192];
  const int t = threadIdx.x;
  const int bm = blockIdx.x, bn = blockIdx.y;
  const int lane = t & 63, w = t >> 6;
  const int wr = w >> 1, wc = w & 1, hi = lane >> 4, l15 = lane & 15;
  const long wbase = (long)bn * 128;

  f32x4 acc[4][4] = {};
  for (int k0 = 0; k0 < 2048; k0 += 32) {
    #pragma unroll
    for (int i = 0; i < 2; ++i) {
      int c = w + 4 * i;
      gl2l(A + (long)(bm * 128 + 16 * c + (lane >> 2)) * 2048 + k0 + (lane & 3) * 8,
           &lds[c * 512]);
      gl2l(W + (wbase + 16 * c + (lane >> 2)) * 2048 + k0 + (lane & 3) * 8,
           &lds[4096 + c * 512]);
    }
    __syncthreads();
    bf16x8 af[4], bff[4];
    #pragma unroll
    for (int m = 0; m < 4; ++m)
      af[m] = *reinterpret_cast<const bf16x8*>(&lds[(wr * 64 + m * 16 + l15) * 32 + hi * 8]);
    #pragma unroll
    for (int n = 0; n < 4; ++n)
      bff[n] = *reinterpret_cast<const bf16x8*>(&lds[4096 + (wc * 64 + n * 16 + l15) * 32 + hi * 8]);
    #pragma unroll
    for (int m = 0; m < 4; ++m)
      #pragma unroll
      for (int n = 0; n < 4; ++n)
        acc[m][n] = mfma16(af[m], bff[n], acc[m][n]);
    __syncthreads();
  }

  #pragma unroll
  for (int m = 0; m < 4; ++m) {
    int row = bm * 128 + wr * 64 + m * 16 + hi * 4;
    #pragma unroll
    for (int n = 0; n < 4; ++n) {
      int col = bn * 128 + wc * 64 + n * 16 + l15;
      #pragma unroll
      for (int r = 0; r < 4; ++r)
        C[(long)(row + r) * 2048 + col] = acc[m][n][r];
    }
  }
}

extern "C" void kernel_launch(void* const* d_in, const int* in_sizes, int n_in,
                              void* d_out, int out_size, void* d_ws, size_t ws_size,
                              hipStream_t stream) {
  const float* x    = (const float*)d_in[0];
  const float* cosb = (const float*)d_in[1];
  const float* sinb = (const float*)d_in[2];
  const float* wq   = (const float*)d_in[3];
  const float* wk   = (const float*)d_in[4];
  const float* wv   = (const float*)d_in[5];
  const float* wo   = (const float*)d_in[6];
  float* out = (float*)d_out;

  char* ws = (char*)d_ws;
  unsigned short* xb  = (unsigned short*)(ws);                 // 16,777,216 B
  unsigned short* wqb = (unsigned short*)(ws + 16777216);      //  8,388,608 B
  unsigned short* wkb = (unsigned short*)(ws + 25165824);      //    524,288 B
  unsigned short* wvb = (unsigned short*)(ws + 25690112);      //    524,288 B
  unsigned short* Qn  = (unsigned short*)(ws + 26214400);      // 16,777,216 B
  unsigned short* Kn  = (unsigned short*)(ws + 42991616);      //  1,048,576 B
  unsigned short* Vn  = (unsigned short*)(ws + 44040192);      //  1,048,576 B
  unsigned short* Vtg = (unsigned short*)(ws + 45088768);      //  1,048,576 B
  unsigned short* wob = (unsigned short*)(ws + 46137344);      //  8,388,608 B
  unsigned short* Ob  = (unsigned short*)ws;                   // alias xb (dead)

  cvt_all<<<dim3(8448), 256, 0, stream>>>(x, wq, wk, wv, wo, xb, wqb, wkb, wvb, wob);
  gemm_qkv<<<dim3(32, 18), 256, 0, stream>>>(xb, wqb, wkb, wvb, cosb, sinb, Qn, Kn, Vn);
  vtrans<<<dim3(32, 2, 2), 256, 0, stream>>>(Vn, Vtg);
  attn2<<<dim3(16, 16, 2), 256, 0, stream>>>(Qn, Kn, Vtg, Ob);
  gemm_out<<<dim3(32, 16), 256, 0, stream>>>(Ob, wob, out);
}